// Round 13
// baseline (194.703 us; speedup 1.0000x reference)
//
#include <hip/hip_runtime.h>

#define B_  2
#define S_  2048
#define D_  1024
#define H_  16
#define HD_ 64
#define M_  4096   // B_*S_

typedef __attribute__((ext_vector_type(8))) short  short8;
typedef __attribute__((ext_vector_type(4))) float  floatx4;

__device__ __forceinline__ unsigned short f2bf(float f) {
  unsigned int u = __float_as_uint(f);
  u = (u + 0x7fffu + ((u >> 16) & 1u)) >> 16;   // RNE
  return (unsigned short)u;
}

// async global->LDS, 16B per lane; lds dest = wave-uniform base + lane*16
__device__ __forceinline__ void gl_lds16(const short* g, short* l) {
  __builtin_amdgcn_global_load_lds(
      (const __attribute__((address_space(1))) unsigned int*)g,
      (__attribute__((address_space(3))) unsigned int*)l, 16, 0, 0);
}

// ---------------------------------------------------------------- cast fp32->bf16
// Exact 1-D grid (4096 blocks): x = blocks [0,2048), each weight = 512 blocks.
__global__ __launch_bounds__(256) void cast_kernel(
    const float* __restrict__ x,  const float* __restrict__ wq,
    const float* __restrict__ wk, const float* __restrict__ wv,
    const float* __restrict__ wo,
    short* __restrict__ xb,  short* __restrict__ wqb, short* __restrict__ wkb,
    short* __restrict__ wvb, short* __restrict__ wob) {
  const int bx = blockIdx.x;
  const float* src; short* dst; int i;
  if (bx < 2048) {                       // x: 524288 groups of 8
    src = x; dst = xb;
    i = bx * 256 + threadIdx.x;
  } else {                               // weights: 131072 groups each
    const int w  = (bx - 2048) >> 9;     // 0..3
    i = ((bx - 2048) & 511) * 256 + threadIdx.x;
    switch (w) {
      case 0:  src = wq; dst = wqb; break;
      case 1:  src = wk; dst = wkb; break;
      case 2:  src = wv; dst = wvb; break;
      default: src = wo; dst = wob; break;
    }
  }
  float4 a = ((const float4*)src)[2 * i];
  float4 b = ((const float4*)src)[2 * i + 1];
  short8 o;
  o[0] = (short)f2bf(a.x); o[1] = (short)f2bf(a.y);
  o[2] = (short)f2bf(a.z); o[3] = (short)f2bf(a.w);
  o[4] = (short)f2bf(b.x); o[5] = (short)f2bf(b.y);
  o[6] = (short)f2bf(b.z); o[7] = (short)f2bf(b.w);
  ((short8*)dst)[i] = o;
}

// ---------------------------------------------------------------- QKV projection
// m97 schedule (CLOSED axis: r2/r5/r6/r8 restructures all regressed) +
// conflict-only slot swizzle (r10) + identity block mapping (CLOSED: r11).
// This round: BM 128->64 (occupancy axis -- the only class with wins:
// r0 attn, r2 gemm_out). Grid (8,64,3) = 1536 blocks = 6/CU, LDS 12KB,
// acc[2][4]. MFMA per CU-step unchanged (8x4x6 = 16x4x3); 6 independent
// drain streams instead of 3 cover the ~600cy/step exposed stall.
// Natural id mapping keeps r11's key property: co-resident {id, id+512,
// id+1024} = same (bn,bm) across z -> co-temporal identical A addresses
// (L1-shared staging). Cost: B staged by 64 bm-blocks (L2-absorbed).
// C[m][n] = sum_k A[m][k]*W[n][k].
// z=0: Q (scaled 0.125*log2e) -> [B,H,S,HD]; z=1: K; z=2: V -> Vt [B,H,HD,S].
__global__ __launch_bounds__(256) void gemm_qkv(
    const short* __restrict__ xb,  const short* __restrict__ wqb,
    const short* __restrict__ wkb, const short* __restrict__ wvb,
    short* __restrict__ qo, short* __restrict__ ko, short* __restrict__ vto) {
  __shared__ alignas(16) short As[64 * 32];    // 4KB, 64B rows, slot-swizzled
  __shared__ alignas(16) short Bs[128 * 32];   // 8KB
  const int tid  = threadIdx.x;
  const int lane = tid & 63, wid = tid >> 6;
  const int quad = lane >> 4, l16 = lane & 15;
  const int bn = blockIdx.x, bm = blockIdx.y, z = blockIdx.z;
  const short* wsel = (z == 0) ? wqb : ((z == 1) ? wkb : wvb);
  const float scale = (z == 0) ? 0.125f * 1.44269504f : 1.0f;
  // staging: chunk tid -> row tid>>2 (0..63), slot tid&3. Source col
  // pre-XORed: (tid>>3)&3 == (row>>1)&3 (also for B's +64 rows: 64/2%4==0).
  const int srow = tid >> 2;
  const int scol = (((tid & 3) ^ ((tid >> 3) & 3))) * 8;     // shorts
  const short* ag0 = xb   + (bm * 64  + srow) * D_ + scol;   // A: 64 rows, 1 call
  const short* bg0 = wsel + (bn * 128 + srow) * D_ + scol;   // B: 128 rows, 2 calls
  const short* bg1 = bg0 + 64 * D_;
  short* la0 = &As[(wid * 16) * 32];           // wave-uniform dest bases
  short* lb0 = &Bs[(wid * 16) * 32];
  short* lb1 = &Bs[(wid * 16 + 64) * 32];
  const int wm = (wid & 1) * 32, wn = (wid >> 1) * 64;
  // swizzled fragment slot: rows = base + l16, base%16==0
  const int sx = (quad ^ ((l16 >> 1) & 3)) * 8;              // per-lane constant
  floatx4 acc[2][4];
#pragma unroll
  for (int i = 0; i < 2; i++)
#pragma unroll
    for (int j = 0; j < 4; j++) acc[i][j] = (floatx4){0.f, 0.f, 0.f, 0.f};

  for (int k0 = 0; k0 < D_; k0 += 32) {
    __syncthreads();
    gl_lds16(ag0 + k0, la0);
    gl_lds16(bg0 + k0, lb0);
    gl_lds16(bg1 + k0, lb1);
    __syncthreads();                 // vmcnt(0) drain -> LDS ready
    short8 af[2], bf[4];
#pragma unroll
    for (int t = 0; t < 2; t++) af[t] = *(const short8*)&As[(wm + t * 16 + l16) * 32 + sx];
#pragma unroll
    for (int t = 0; t < 4; t++) bf[t] = *(const short8*)&Bs[(wn + t * 16 + l16) * 32 + sx];
#pragma unroll
    for (int tm = 0; tm < 2; tm++)
#pragma unroll
      for (int tn = 0; tn < 4; tn++)
        acc[tm][tn] = __builtin_amdgcn_mfma_f32_16x16x32_bf16(af[tm], bf[tn], acc[tm][tn], 0, 0, 0);
  }
#pragma unroll
  for (int tm = 0; tm < 2; tm++) {
#pragma unroll
    for (int tn = 0; tn < 4; tn++) {
      int n = bn * 128 + wn + tn * 16 + l16;
      int h = n >> 6, hd = n & 63;
#pragma unroll
      for (int r = 0; r < 4; r++) {
        int m = bm * 64 + wm + tm * 16 + quad * 4 + r;
        int b = m >> 11, s = m & 2047;
        unsigned short val = f2bf(acc[tm][tn][r] * scale);
        if (z == 2)       // Vt [B,H,HD,S]
          vto[((b * H_ + h) * HD_ + hd) * S_ + s] = (short)val;
        else if (z == 1)
          ko[((b * H_ + h) * S_ + s) * HD_ + hd] = (short)val;
        else
          qo[((b * H_ + h) * S_ + s) * HD_ + hd] = (short)val;
      }
    }
  }
}

// ---------------------------------------------------------------- output projection
// 64x64 tile -> grid (16,64) = 1024 blocks = 4 independent blocks/CU
// (extends the proven r2-r4 1->2 blocks/CU mechanism). acc[2][2] per wave;
// 2 gl_lds per K-step; conflict-only slot swizzle (r10).
__global__ __launch_bounds__(256) void gemm_out(
    const short* __restrict__ cx, const short* __restrict__ wob,
    const float* __restrict__ bo, float* __restrict__ out) {
  __shared__ alignas(16) short As[64 * 32];
  __shared__ alignas(16) short Bs[64 * 32];
  const int tid  = threadIdx.x;
  const int lane = tid & 63, wid = tid >> 6;
  const int quad = lane >> 4, l16 = lane & 15;
  const int bn = blockIdx.x, bm = blockIdx.y;
  const int srow = tid >> 2;
  const int scol = (((tid & 3) ^ ((tid >> 3) & 3))) * 8;
  const short* ag0 = cx  + (bm * 64 + srow) * D_ + scol;
  const short* bg0 = wob + (bn * 64 + srow) * D_ + scol;
  short* la0 = &As[(wid * 16) * 32];
  short* lb0 = &Bs[(wid * 16) * 32];
  const int wm = (wid & 1) * 32, wn = (wid >> 1) * 32;
  const int sx = (quad ^ ((l16 >> 1) & 3)) * 8;
  floatx4 acc[2][2];
#pragma unroll
  for (int i = 0; i < 2; i++)
#pragma unroll
    for (int j = 0; j < 2; j++) acc[i][j] = (floatx4){0.f, 0.f, 0.f, 0.f};

  for (int k0 = 0; k0 < D_; k0 += 32) {
    __syncthreads();
    gl_lds16(ag0 + k0, la0);
    gl_lds16(bg0 + k0, lb0);
    __syncthreads();
    short8 af[2], bf[2];
#pragma unroll
    for (int t = 0; t < 2; t++) af[t] = *(const short8*)&As[(wm + t * 16 + l16) * 32 + sx];
#pragma unroll
    for (int t = 0; t < 2; t++) bf[t] = *(const short8*)&Bs[(wn + t * 16 + l16) * 32 + sx];
#pragma unroll
    for (int tm = 0; tm < 2; tm++)
#pragma unroll
      for (int tn = 0; tn < 2; tn++)
        acc[tm][tn] = __builtin_amdgcn_mfma_f32_16x16x32_bf16(af[tm], bf[tn], acc[tm][tn], 0, 0, 0);
  }
#pragma unroll
  for (int tn = 0; tn < 2; tn++) {
    int n = bn * 64 + wn + tn * 16 + l16;
    float bias = bo[n];
#pragma unroll
    for (int tm = 0; tm < 2; tm++) {
#pragma unroll
      for (int r = 0; r < 4; r++) {
        int m = bm * 64 + wm + tm * 16 + quad * 4 + r;
        out[m * D_ + n] = acc[tm][tn][r] + bias;
      }
    }
  }
}

// ---------------------------------------------------------------- flash attention
// 8-wave / 512-thread blocks, 128-row Q tile per block (16 rows per wave),
// KVBLK=64. K/V double-buffered in LDS + register prefetch -> ONE barrier
// per tile; XOR swizzle (16B slot ^= row&7) on K/V/P; QK acc seeded -32
// (fixed-rebase softmax); per-CU-balanced qt mapping; T5 setprio around
// the MFMA clusters.
__global__ __launch_bounds__(512) void attn_kernel(
    const short* __restrict__ qbuf, const short* __restrict__ kbuf,
    const short* __restrict__ vtbuf, short* __restrict__ ctx) {
  __shared__ alignas(16) short Ks[2][64][64];   // [buf][s][hd], swizzled
  __shared__ alignas(16) short Vs[2][64][64];   // [buf][hd][s], swizzled
  __shared__ alignas(16) short Ps[8][16][64];   // per-wave P, swizzled
  const int tid  = threadIdx.x;
  const int lane = tid & 63, wid = tid >> 6;        // wid 0..7
  const int quad = lane >> 4, l16 = lane & 15;
  const int bx = blockIdx.x, by = blockIdx.y;       // (16, 32)
  const int qt = ((by >> 4) & 1) ? bx : (15 - bx);  // balanced depth per CU
  const int bh = by;
  const int base = bh * (S_ * HD_);
  const int q0 = qt * 128 + wid * 16;               // wave's first q row
  const int NT = 2 * qt + 2;                        // KV tiles (64 wide)

  short8 qf0 = *(const short8*)(qbuf + base + (q0 + l16) * HD_ + quad * 8);
  short8 qf1 = *(const short8*)(qbuf + base + (q0 + l16) * HD_ + 32 + quad * 8);

  float lsum[4];
  floatx4 o[4];
#pragma unroll
  for (int r = 0; r < 4; r++) lsum[r] = 0.f;
#pragma unroll
  for (int nt = 0; nt < 4; nt++) o[nt] = (floatx4){0.f, 0.f, 0.f, 0.f};

  // staging: 512 threads x one 16B K elem + one 16B V elem = full 8KB+8KB tile
  const int srow  = tid >> 3;                       // 0..63
  const int sslot = tid & 7;                        // 16B slot 0..7
  const int swz   = ((sslot ^ (srow & 7)) << 3);    // swizzled short offset
  const short* kg = kbuf  + base + srow * HD_ + sslot * 8;
  const short* vg = vtbuf + base + srow * S_  + sslot * 8;   // srow = hd

  short8 kreg = *(const short8*)(kg);               // tile 0
  short8 vreg = *(const short8*)(vg);
  *(short8*)&Ks[0][srow][swz] = kreg;
  *(short8*)&Vs[0][srow][swz] = vreg;
  kreg = *(const short8*)(kg + 64 * HD_);           // tile 1 (NT >= 2 always)
  vreg = *(const short8*)(vg + 64);
  __syncthreads();                                  // tile 0 visible

  const int x16 = l16 & 7;
  for (int kt = 0; kt < NT; kt++) {
    const int b = kt & 1;
    if (kt + 1 < NT) {        // stage tile kt+1 into other buffer (overlaps compute)
      *(short8*)&Ks[b ^ 1][srow][swz] = kreg;
      *(short8*)&Vs[b ^ 1][srow][swz] = vreg;
    }
    if (kt + 2 < NT) {        // prefetch tile kt+2 into regs
      kreg = *(const short8*)(kg + (kt + 2) * 64 * HD_);
      vreg = *(const short8*)(vg + (kt + 2) * 64);
    }
    if (kt * 64 <= q0 + 15) {               // wave has unmasked work this tile
      floatx4 sc[4];
      __builtin_amdgcn_s_setprio(1);
#pragma unroll
      for (int ct = 0; ct < 4; ct++) {
        int row = ct * 16 + l16, rx = row & 7;
        short8 kb0 = *(const short8*)&Ks[b][row][(quad ^ rx) << 3];
        short8 kb1 = *(const short8*)&Ks[b][row][((4 + quad) ^ rx) << 3];
        floatx4 zz = (floatx4){-32.f, -32.f, -32.f, -32.f};   // rebase seed
        zz     = __builtin_amdgcn_mfma_f32_16x16x32_bf16(qf0, kb0, zz, 0, 0, 0);
        sc[ct] = __builtin_amdgcn_mfma_f32_16x16x32_bf16(qf1, kb1, zz, 0, 0, 0);
      }
      __builtin_amdgcn_s_setprio(0);
      if (kt * 64 + 63 > q0) {              // causal mask (2^-inf = 0)
#pragma unroll
        for (int ct = 0; ct < 4; ct++)
#pragma unroll
          for (int r = 0; r < 4; r++)
            if (kt * 64 + ct * 16 + l16 > q0 + quad * 4 + r) sc[ct][r] = -INFINITY;
      }
#pragma unroll
      for (int r = 0; r < 4; r++) {
        int prow = quad * 4 + r, px = prow & 7;
#pragma unroll
        for (int ct = 0; ct < 4; ct++) {
          float p = __builtin_amdgcn_exp2f(sc[ct][r]);
          lsum[r] += p;
          int cslot = ct * 2 + (l16 >> 3);
          // truncating bf16 (p >= 0): 1 op vs 3 for RNE
          Ps[wid][prow][((cslot ^ px) << 3) + x16] = (short)(__float_as_uint(p) >> 16);
        }
      }
      // PV: o += P[16x64] * V[64x64]   (Ps wave-local; lgkmcnt orders it)
      __builtin_amdgcn_s_setprio(1);
#pragma unroll
      for (int ks = 0; ks < 2; ks++) {
        short8 pa = *(const short8*)&Ps[wid][l16][((ks * 4 + quad) ^ x16) << 3];
#pragma unroll
        for (int nt = 0; nt < 4; nt++) {
          int vrow = nt * 16 + l16;
          short8 vb = *(const short8*)&Vs[b][vrow][((ks * 4 + quad) ^ (vrow & 7)) << 3];
          o[nt] = __builtin_amdgcn_mfma_f32_16x16x32_bf16(pa, vb, o[nt], 0, 0, 0);
        }
      }
      __builtin_amdgcn_s_setprio(0);
    }
    __syncthreads();   // reads of buf[b] done + writes of buf[b^1] visible
  }
  // epilogue: one cross-lane l reduction, then ctx[b*2048+s][h*64+col] = o/l
#pragma unroll
  for (int r = 0; r < 4; r++) {
    float ls = lsum[r];
    ls += __shfl_xor(ls, 1);
    ls += __shfl_xor(ls, 2);
    ls += __shfl_xor(ls, 4);
    ls += __shfl_xor(ls, 8);
    float linv = 1.f / ls;
    int s = q0 + quad * 4 + r;
    int rowbase = ((bh >> 4) * S_ + s) * D_ + (bh & 15) * HD_;
#pragma unroll
    for (int nt = 0; nt < 4; nt++)
      ctx[rowbase + nt * 16 + l16] = (short)f2bf(o[nt][r] * linv);
  }
}

// ---------------------------------------------------------------- launch
extern "C" void kernel_launch(void* const* d_in, const int* in_sizes, int n_in,
                              void* d_out, int out_size, void* d_ws, size_t ws_size,
                              hipStream_t stream) {
  const float* x  = (const float*)d_in[0];
  const float* wq = (const float*)d_in[1];
  const float* wk = (const float*)d_in[2];
  const float* wv = (const float*)d_in[3];
  const float* wo = (const float*)d_in[4];
  const float* bo = (const float*)d_in[5];
  float* out = (float*)d_out;

  char* ws = (char*)d_ws;
  short* xb  = (short*)(ws);                    // 8 MB
  short* wqb = (short*)(ws + (8u  << 20));      // 2 MB
  short* wkb = (short*)(ws + (10u << 20));      // 2 MB
  short* wvb = (short*)(ws + (12u << 20));      // 2 MB
  short* wob = (short*)(ws + (14u << 20));      // 2 MB
  short* qb  = (short*)(ws + (16u << 20));      // 8 MB  [B,H,S,HD]
  short* kb  = (short*)(ws + (24u << 20));      // 8 MB  [B,H,S,HD]
  short* cx  = (short*)(ws + (32u << 20));      // 8 MB  [M,D]
  short* vtb = (short*)(ws + (40u << 20));      // 8 MB  [B,H,HD,S] -> total 48 MB

  cast_kernel<<<dim3(4096),      256, 0, stream>>>(x, wq, wk, wv, wo, xb, wqb, wkb, wvb, wob);
  gemm_qkv   <<<dim3(8, 64, 3),  256, 0, stream>>>(xb, wqb, wkb, wvb, qb, kb, vtb);
  attn_kernel<<<dim3(16, 32),    512, 0, stream>>>(qb, kb, vtb, cx);
  gemm_out   <<<dim3(16, 64),    256, 0, stream>>>(cx, wob, bo, out);
}

// Round 14
// 173.428 us; speedup vs baseline: 1.1227x; 1.1227x over previous
//
#include <hip/hip_runtime.h>

#define B_  2
#define S_  2048
#define D_  1024
#define H_  16
#define HD_ 64
#define M_  4096   // B_*S_

typedef __attribute__((ext_vector_type(8))) short  short8;
typedef __attribute__((ext_vector_type(4))) float  floatx4;

__device__ __forceinline__ unsigned short f2bf(float f) {
  unsigned int u = __float_as_uint(f);
  u = (u + 0x7fffu + ((u >> 16) & 1u)) >> 16;   // RNE
  return (unsigned short)u;
}

// async global->LDS, 16B per lane; lds dest = wave-uniform base + lane*16
__device__ __forceinline__ void gl_lds16(const short* g, short* l) {
  __builtin_amdgcn_global_load_lds(
      (const __attribute__((address_space(1))) unsigned int*)g,
      (__attribute__((address_space(3))) unsigned int*)l, 16, 0, 0);
}

// ---------------------------------------------------------------- cast fp32->bf16
// Exact 1-D grid (4096 blocks): x = blocks [0,2048), each weight = 512 blocks.
__global__ __launch_bounds__(256) void cast_kernel(
    const float* __restrict__ x,  const float* __restrict__ wq,
    const float* __restrict__ wk, const float* __restrict__ wv,
    const float* __restrict__ wo,
    short* __restrict__ xb,  short* __restrict__ wqb, short* __restrict__ wkb,
    short* __restrict__ wvb, short* __restrict__ wob) {
  const int bx = blockIdx.x;
  const float* src; short* dst; int i;
  if (bx < 2048) {                       // x: 524288 groups of 8
    src = x; dst = xb;
    i = bx * 256 + threadIdx.x;
  } else {                               // weights: 131072 groups each
    const int w  = (bx - 2048) >> 9;     // 0..3
    i = ((bx - 2048) & 511) * 256 + threadIdx.x;
    switch (w) {
      case 0:  src = wq; dst = wqb; break;
      case 1:  src = wk; dst = wkb; break;
      case 2:  src = wv; dst = wvb; break;
      default: src = wo; dst = wob; break;
    }
  }
  float4 a = ((const float4*)src)[2 * i];
  float4 b = ((const float4*)src)[2 * i + 1];
  short8 o;
  o[0] = (short)f2bf(a.x); o[1] = (short)f2bf(a.y);
  o[2] = (short)f2bf(a.z); o[3] = (short)f2bf(a.w);
  o[4] = (short)f2bf(b.x); o[5] = (short)f2bf(b.y);
  o[6] = (short)f2bf(b.z); o[7] = (short)f2bf(b.w);
  ((short8*)dst)[i] = o;
}

// ---------------------------------------------------------------- QKV projection
// FINAL (r12 state, session best 173.6 us): m97 structure, BK=32, 128x128
// tile, 768 blocks = 3/CU + conflict-only slot swizzle (r10: conflicts
// 3.15M -> 0, qkv below the ~43us fill cutoff).
// CLOSED AXES (all by direct measurement -- do not revisit):
//  - K-loop schedule: 8-phase 64us (r2), BK64+swz 59 (r5), 2ph-dbuf 52 (r6),
//    4-ring vmcnt 99 (r8). Implicit 3-blocks/CU overlap wins at this shape.
//  - Block placement: XCD-chunked remap (r11) cut FETCH 35.9->22.6MB but
//    dur 43->52.4 (NOT fetch-bound). Natural id keeps same-(bn,bm)/diff-z
//    blocks co-resident -> co-temporal identical A addresses -> L1-shared
//    staging drains. Keep identity mapping.
//  - Tile shape: BM 128->64 (r13) raised occupancy 25->34% but halved MFMA
//    per drain event and doubled per-CU drain count; FETCH +70% (W read by
//    2x more blocks); 72-77us. Keep 128x128.
// C[m][n] = sum_k A[m][k]*W[n][k].
// z=0: Q (scaled 0.125*log2e) -> [B,H,S,HD]; z=1: K; z=2: V -> Vt [B,H,HD,S].
__global__ __launch_bounds__(256) void gemm_qkv(
    const short* __restrict__ xb,  const short* __restrict__ wqb,
    const short* __restrict__ wkb, const short* __restrict__ wvb,
    short* __restrict__ qo, short* __restrict__ ko, short* __restrict__ vto) {
  __shared__ alignas(16) short As[128 * 32];   // row-major, 64B/row, slot-swizzled
  __shared__ alignas(16) short Bs[128 * 32];
  const int tid  = threadIdx.x;
  const int lane = tid & 63, wid = tid >> 6;
  const int quad = lane >> 4, l16 = lane & 15;
  const int bn = blockIdx.x, bm = blockIdx.y, z = blockIdx.z;
  const short* wsel = (z == 0) ? wqb : ((z == 1) ? wkb : wvb);
  const float scale = (z == 0) ? 0.125f * 1.44269504f : 1.0f;
  const int lrow = wid * 32 + (lane >> 2);
  // pre-swizzled source col: LDS(row, s) = G(row, s ^ ((row>>1)&3));
  // staged row (lane>>2) (+16 for chunk1) -> (row>>1)&3 = (lane>>3)&3 both chunks
  const int lcol = (((lane & 3) ^ ((lane >> 3) & 3))) * 8;   // shorts
  const short* ag0 = xb   + (bm * 128 + lrow) * D_ + lcol;
  const short* ag1 = ag0 + 16 * D_;
  const short* bg0 = wsel + (bn * 128 + lrow) * D_ + lcol;
  const short* bg1 = bg0 + 16 * D_;
  short* la0 = &As[(wid * 32) * 32];
  short* la1 = &As[(wid * 32 + 16) * 32];
  short* lb0 = &Bs[(wid * 32) * 32];
  short* lb1 = &Bs[(wid * 32 + 16) * 32];
  const int wm = (wid & 1) * 64, wn = (wid >> 1) * 64;
  // swizzled fragment slot: want G(row, quad); row = base+l16, base%16==0
  const int sx = (quad ^ ((l16 >> 1) & 3)) * 8;              // per-lane constant
  floatx4 acc[4][4];
#pragma unroll
  for (int i = 0; i < 4; i++)
#pragma unroll
    for (int j = 0; j < 4; j++) acc[i][j] = (floatx4){0.f, 0.f, 0.f, 0.f};

  for (int k0 = 0; k0 < D_; k0 += 32) {
    __syncthreads();
    gl_lds16(ag0 + k0, la0);
    gl_lds16(ag1 + k0, la1);
    gl_lds16(bg0 + k0, lb0);
    gl_lds16(bg1 + k0, lb1);
    __syncthreads();                 // vmcnt(0) drain -> LDS ready
    short8 af[4], bf[4];
#pragma unroll
    for (int t = 0; t < 4; t++) af[t] = *(const short8*)&As[(wm + t * 16 + l16) * 32 + sx];
#pragma unroll
    for (int t = 0; t < 4; t++) bf[t] = *(const short8*)&Bs[(wn + t * 16 + l16) * 32 + sx];
#pragma unroll
    for (int tm = 0; tm < 4; tm++)
#pragma unroll
      for (int tn = 0; tn < 4; tn++)
        acc[tm][tn] = __builtin_amdgcn_mfma_f32_16x16x32_bf16(af[tm], bf[tn], acc[tm][tn], 0, 0, 0);
  }
#pragma unroll
  for (int tm = 0; tm < 4; tm++) {
#pragma unroll
    for (int tn = 0; tn < 4; tn++) {
      int n = bn * 128 + wn + tn * 16 + l16;
      int h = n >> 6, hd = n & 63;
#pragma unroll
      for (int r = 0; r < 4; r++) {
        int m = bm * 128 + wm + tm * 16 + quad * 4 + r;
        int b = m >> 11, s = m & 2047;
        unsigned short val = f2bf(acc[tm][tn][r] * scale);
        if (z == 2)       // Vt [B,H,HD,S]
          vto[((b * H_ + h) * HD_ + hd) * S_ + s] = (short)val;
        else if (z == 1)
          ko[((b * H_ + h) * S_ + s) * HD_ + hd] = (short)val;
        else
          qo[((b * H_ + h) * S_ + s) * HD_ + hd] = (short)val;
      }
    }
  }
}

// ---------------------------------------------------------------- output projection
// 128x64 tile -> grid (16,32) = 512 blocks = 2 independent blocks/CU.
// acc[4][2] per wave; 3 gl_lds per K-step. Conflict-only slot swizzle (r10).
// Identity block mapping (r11) and 128-row tile (r13 64x64 bundled in the
// qkv regression -- reverted with it).
__global__ __launch_bounds__(256) void gemm_out(
    const short* __restrict__ cx, const short* __restrict__ wob,
    const float* __restrict__ bo, float* __restrict__ out) {
  __shared__ alignas(16) short As[128 * 32];
  __shared__ alignas(16) short Bs[64 * 32];
  const int tid  = threadIdx.x;
  const int lane = tid & 63, wid = tid >> 6;
  const int quad = lane >> 4, l16 = lane & 15;
  const int bn = blockIdx.x, bm = blockIdx.y;
  const int lrow = wid * 32 + (lane >> 2);
  const int lcol = (((lane & 3) ^ ((lane >> 3) & 3))) * 8;
  const short* ag0 = cx  + (bm * 128 + lrow) * D_ + lcol;
  const short* ag1 = ag0 + 16 * D_;
  const short* bg0 = wob + (bn * 64 + wid * 16 + (lane >> 2)) * D_ + lcol;
  short* la0 = &As[(wid * 32) * 32];
  short* la1 = &As[(wid * 32 + 16) * 32];
  short* lb0 = &Bs[(wid * 16) * 32];
  const int wm = (wid & 1) * 64, wn = (wid >> 1) * 32;
  const int sx = (quad ^ ((l16 >> 1) & 3)) * 8;
  floatx4 acc[4][2];
#pragma unroll
  for (int i = 0; i < 4; i++)
#pragma unroll
    for (int j = 0; j < 2; j++) acc[i][j] = (floatx4){0.f, 0.f, 0.f, 0.f};

  for (int k0 = 0; k0 < D_; k0 += 32) {
    __syncthreads();
    gl_lds16(ag0 + k0, la0);
    gl_lds16(ag1 + k0, la1);
    gl_lds16(bg0 + k0, lb0);
    __syncthreads();
    short8 af[4], bf[2];
#pragma unroll
    for (int t = 0; t < 4; t++) af[t] = *(const short8*)&As[(wm + t * 16 + l16) * 32 + sx];
#pragma unroll
    for (int t = 0; t < 2; t++) bf[t] = *(const short8*)&Bs[(wn + t * 16 + l16) * 32 + sx];
#pragma unroll
    for (int tm = 0; tm < 4; tm++)
#pragma unroll
      for (int tn = 0; tn < 2; tn++)
        acc[tm][tn] = __builtin_amdgcn_mfma_f32_16x16x32_bf16(af[tm], bf[tn], acc[tm][tn], 0, 0, 0);
  }
#pragma unroll
  for (int tn = 0; tn < 2; tn++) {
    int n = bn * 64 + wn + tn * 16 + l16;
    float bias = bo[n];
#pragma unroll
    for (int tm = 0; tm < 4; tm++) {
#pragma unroll
      for (int r = 0; r < 4; r++) {
        int m = bm * 128 + wm + tm * 16 + quad * 4 + r;
        out[m * D_ + n] = acc[tm][tn][r] + bias;
      }
    }
  }
}

// ---------------------------------------------------------------- flash attention
// 8-wave / 512-thread blocks, 128-row Q tile per block (16 rows per wave),
// KVBLK=64. K/V double-buffered in LDS + register prefetch -> ONE barrier
// per tile; XOR swizzle (16B slot ^= row&7) on K/V/P; QK acc seeded -32
// (fixed-rebase softmax); per-CU-balanced qt mapping; T5 setprio around
// the MFMA clusters.
__global__ __launch_bounds__(512) void attn_kernel(
    const short* __restrict__ qbuf, const short* __restrict__ kbuf,
    const short* __restrict__ vtbuf, short* __restrict__ ctx) {
  __shared__ alignas(16) short Ks[2][64][64];   // [buf][s][hd], swizzled
  __shared__ alignas(16) short Vs[2][64][64];   // [buf][hd][s], swizzled
  __shared__ alignas(16) short Ps[8][16][64];   // per-wave P, swizzled
  const int tid  = threadIdx.x;
  const int lane = tid & 63, wid = tid >> 6;        // wid 0..7
  const int quad = lane >> 4, l16 = lane & 15;
  const int bx = blockIdx.x, by = blockIdx.y;       // (16, 32)
  const int qt = ((by >> 4) & 1) ? bx : (15 - bx);  // balanced depth per CU
  const int bh = by;
  const int base = bh * (S_ * HD_);
  const int q0 = qt * 128 + wid * 16;               // wave's first q row
  const int NT = 2 * qt + 2;                        // KV tiles (64 wide)

  short8 qf0 = *(const short8*)(qbuf + base + (q0 + l16) * HD_ + quad * 8);
  short8 qf1 = *(const short8*)(qbuf + base + (q0 + l16) * HD_ + 32 + quad * 8);

  float lsum[4];
  floatx4 o[4];
#pragma unroll
  for (int r = 0; r < 4; r++) lsum[r] = 0.f;
#pragma unroll
  for (int nt = 0; nt < 4; nt++) o[nt] = (floatx4){0.f, 0.f, 0.f, 0.f};

  // staging: 512 threads x one 16B K elem + one 16B V elem = full 8KB+8KB tile
  const int srow  = tid >> 3;                       // 0..63
  const int sslot = tid & 7;                        // 16B slot 0..7
  const int swz   = ((sslot ^ (srow & 7)) << 3);    // swizzled short offset
  const short* kg = kbuf  + base + srow * HD_ + sslot * 8;
  const short* vg = vtbuf + base + srow * S_  + sslot * 8;   // srow = hd

  short8 kreg = *(const short8*)(kg);               // tile 0
  short8 vreg = *(const short8*)(vg);
  *(short8*)&Ks[0][srow][swz] = kreg;
  *(short8*)&Vs[0][srow][swz] = vreg;
  kreg = *(const short8*)(kg + 64 * HD_);           // tile 1 (NT >= 2 always)
  vreg = *(const short8*)(vg + 64);
  __syncthreads();                                  // tile 0 visible

  const int x16 = l16 & 7;
  for (int kt = 0; kt < NT; kt++) {
    const int b = kt & 1;
    if (kt + 1 < NT) {        // stage tile kt+1 into other buffer (overlaps compute)
      *(short8*)&Ks[b ^ 1][srow][swz] = kreg;
      *(short8*)&Vs[b ^ 1][srow][swz] = vreg;
    }
    if (kt + 2 < NT) {        // prefetch tile kt+2 into regs
      kreg = *(const short8*)(kg + (kt + 2) * 64 * HD_);
      vreg = *(const short8*)(vg + (kt + 2) * 64);
    }
    if (kt * 64 <= q0 + 15) {               // wave has unmasked work this tile
      floatx4 sc[4];
      __builtin_amdgcn_s_setprio(1);
#pragma unroll
      for (int ct = 0; ct < 4; ct++) {
        int row = ct * 16 + l16, rx = row & 7;
        short8 kb0 = *(const short8*)&Ks[b][row][(quad ^ rx) << 3];
        short8 kb1 = *(const short8*)&Ks[b][row][((4 + quad) ^ rx) << 3];
        floatx4 zz = (floatx4){-32.f, -32.f, -32.f, -32.f};   // rebase seed
        zz     = __builtin_amdgcn_mfma_f32_16x16x32_bf16(qf0, kb0, zz, 0, 0, 0);
        sc[ct] = __builtin_amdgcn_mfma_f32_16x16x32_bf16(qf1, kb1, zz, 0, 0, 0);
      }
      __builtin_amdgcn_s_setprio(0);
      if (kt * 64 + 63 > q0) {              // causal mask (2^-inf = 0)
#pragma unroll
        for (int ct = 0; ct < 4; ct++)
#pragma unroll
          for (int r = 0; r < 4; r++)
            if (kt * 64 + ct * 16 + l16 > q0 + quad * 4 + r) sc[ct][r] = -INFINITY;
      }
#pragma unroll
      for (int r = 0; r < 4; r++) {
        int prow = quad * 4 + r, px = prow & 7;
#pragma unroll
        for (int ct = 0; ct < 4; ct++) {
          float p = __builtin_amdgcn_exp2f(sc[ct][r]);
          lsum[r] += p;
          int cslot = ct * 2 + (l16 >> 3);
          // truncating bf16 (p >= 0): 1 op vs 3 for RNE
          Ps[wid][prow][((cslot ^ px) << 3) + x16] = (short)(__float_as_uint(p) >> 16);
        }
      }
      // PV: o += P[16x64] * V[64x64]   (Ps wave-local; lgkmcnt orders it)
      __builtin_amdgcn_s_setprio(1);
#pragma unroll
      for (int ks = 0; ks < 2; ks++) {
        short8 pa = *(const short8*)&Ps[wid][l16][((ks * 4 + quad) ^ x16) << 3];
#pragma unroll
        for (int nt = 0; nt < 4; nt++) {
          int vrow = nt * 16 + l16;
          short8 vb = *(const short8*)&Vs[b][vrow][((ks * 4 + quad) ^ (vrow & 7)) << 3];
          o[nt] = __builtin_amdgcn_mfma_f32_16x16x32_bf16(pa, vb, o[nt], 0, 0, 0);
        }
      }
      __builtin_amdgcn_s_setprio(0);
    }
    __syncthreads();   // reads of buf[b] done + writes of buf[b^1] visible
  }
  // epilogue: one cross-lane l reduction, then ctx[b*2048+s][h*64+col] = o/l
#pragma unroll
  for (int r = 0; r < 4; r++) {
    float ls = lsum[r];
    ls += __shfl_xor(ls, 1);
    ls += __shfl_xor(ls, 2);
    ls += __shfl_xor(ls, 4);
    ls += __shfl_xor(ls, 8);
    float linv = 1.f / ls;
    int s = q0 + quad * 4 + r;
    int rowbase = ((bh >> 4) * S_ + s) * D_ + (bh & 15) * HD_;
#pragma unroll
    for (int nt = 0; nt < 4; nt++)
      ctx[rowbase + nt * 16 + l16] = (short)f2bf(o[nt][r] * linv);
  }
}

// ---------------------------------------------------------------- launch
extern "C" void kernel_launch(void* const* d_in, const int* in_sizes, int n_in,
                              void* d_out, int out_size, void* d_ws, size_t ws_size,
                              hipStream_t stream) {
  const float* x  = (const float*)d_in[0];
  const float* wq = (const float*)d_in[1];
  const float* wk = (const float*)d_in[2];
  const float* wv = (const float*)d_in[3];
  const float* wo = (const float*)d_in[4];
  const float* bo = (const float*)d_in[5];
  float* out = (float*)d_out;

  char* ws = (char*)d_ws;
  short* xb  = (short*)(ws);                    // 8 MB
  short* wqb = (short*)(ws + (8u  << 20));      // 2 MB
  short* wkb = (short*)(ws + (10u << 20));      // 2 MB
  short* wvb = (short*)(ws + (12u << 20));      // 2 MB
  short* wob = (short*)(ws + (14u << 20));      // 2 MB
  short* qb  = (short*)(ws + (16u << 20));      // 8 MB  [B,H,S,HD]
  short* kb  = (short*)(ws + (24u << 20));      // 8 MB  [B,H,S,HD]
  short* cx  = (short*)(ws + (32u << 20));      // 8 MB  [M,D]
  short* vtb = (short*)(ws + (40u << 20));      // 8 MB  [B,H,HD,S] -> total 48 MB

  cast_kernel<<<dim3(4096),     256, 0, stream>>>(x, wq, wk, wv, wo, xb, wqb, wkb, wvb, wob);
  gemm_qkv   <<<dim3(8, 32, 3), 256, 0, stream>>>(xb, wqb, wkb, wvb, qb, kb, vtb);
  attn_kernel<<<dim3(16, 32),   512, 0, stream>>>(qb, kb, vtb, cx);
  gemm_out   <<<dim3(16, 32),   256, 0, stream>>>(cx, wob, bo, out);
}